// Round 16
// baseline (106.793 us; speedup 1.0000x reference)
//
#include <hip/hip_runtime.h>

// Chamfer distance via MFMA — R16: fused one-pass, RS=1, B-fragments read
// DIRECTLY FROM GLOBAL (L1/L2), no LDS staging, no main-loop barriers.
// d2(i,j) = xsq_i + ysq_j - 2 x.y in one 32x32x16 bf16 MFMA via split-bf16
// K-slots (packing verified since R6, absmax 0.0).
//
// R15 post-mortem: __shfl_xor runs on the DS pipe -> fused-with-LDS-staging
// had the same DS-pipe load as row-only R11 (the binding pipe all session).
// Fix: y-records stream from global (262MB via L1, ~64MB via L2, ~3.5us on
// the idle VMEM pipe); DS pipe keeps only the col machinery (~4us).
// Grid 32x16x2 = 1024 blocks = 16 waves/CU. colp[4][2048]=32KB, each slot
// written exactly once per sweep (no init), merged once at kernel end.
// Zero contended atomics (R9); allocator-safe RS=1 + d0/d1 shape (R9/R11).

typedef __attribute__((ext_vector_type(8))) short bf16x8;
typedef __attribute__((ext_vector_type(16))) float floatx16;

#define BB 16
#define NN 4096
#define T  256
#define NPTS (BB * NN)       // 65536
#define XC 128               // x per block (4 waves x 1 strip)
#define NXB (NN / XC)        // 32
#define YS 2                 // y halves
#define YH (NN / YS)         // 2048 y per block
#define NTL (YH / 32)        // 64 tiles per sweep
#define ONEBF 0x3F80u

__device__ __forceinline__ unsigned int f2bf(float f) {
    unsigned int u = __float_as_uint(f);
    u += 0x7fffu + ((u >> 16) & 1u);     // RNE to bf16
    return u >> 16;
}
__device__ __forceinline__ float bf2f(unsigned int h) {
    return __uint_as_float(h << 16);
}
__device__ __forceinline__ float tree16(const floatx16& d) {
    float t0 = fminf(fminf(d[0], d[1]), d[2]);      // -> v_min3_f32
    float t1 = fminf(fminf(d[3], d[4]), d[5]);
    float t2 = fminf(fminf(d[6], d[7]), d[8]);
    float t3 = fminf(fminf(d[9], d[10]), d[11]);
    float t4 = fminf(fminf(d[12], d[13]), d[14]);
    float u0 = fminf(fminf(t0, t1), t2);
    float u1 = fminf(fminf(t3, t4), d[15]);
    return fminf(u0, u1);
}

// ---- prep: build 32B y-records for TARGET (y side of the fused sweep)
__global__ __launch_bounds__(T) void chamfer_prep(
    const float* __restrict__ target,
    uint4* __restrict__ rec0, uint4* __restrict__ rec1)
{
    int g = blockIdx.x * T + threadIdx.x;        // 0 .. NPTS-1
    const float* yp = target + (size_t)g * 3;
    float y0 = yp[0], y1 = yp[1], y2 = yp[2];
    unsigned int h0 = f2bf(y0), h1 = f2bf(y1), h2 = f2bf(y2);
    unsigned int H0 = f2bf(-2.f * bf2f(h0));
    unsigned int H1 = f2bf(-2.f * bf2f(h1));
    unsigned int H2 = f2bf(-2.f * bf2f(h2));
    unsigned int L0 = f2bf(-2.f * (y0 - bf2f(h0)));
    unsigned int L1 = f2bf(-2.f * (y1 - bf2f(h1)));
    unsigned int L2 = f2bf(-2.f * (y2 - bf2f(h2)));
    float ysq = fmaf(y0, y0, fmaf(y1, y1, y2 * y2));
    unsigned int sh = f2bf(ysq);
    unsigned int sl = f2bf(ysq - bf2f(sh));
    rec0[g] = make_uint4(H0 | (H1 << 16), H2 | (H0 << 16),
                         H1 | (H2 << 16), L0 | (L1 << 16));   // k0..7
    rec1[g] = make_uint4(L2 | (ONEBF << 16), ONEBF | (sh << 16),
                         sl, 0u);                             // k8..15
}

// ---- main: 128 pred-x vs 2048 target-y, B from global; rows + col slices
__global__ __launch_bounds__(T, 2) void chamfer_main(
    const float* __restrict__ pred,
    const uint4* __restrict__ rec0, const uint4* __restrict__ rec1,
    float* __restrict__ rowp,       // [BB][YS][NN] partial row mins
    float* __restrict__ colf)       // [BB][YS][NXB][YH] partial col mins
{
    __shared__ float colp[4][YH];       // 32 KiB, per-wave col mins

    const int xb = blockIdx.x;
    const int b  = blockIdx.y;
    const int ys = blockIdx.z;
    const int tid  = threadIdx.x;
    const int lane = tid & 63, w = tid >> 6;
    const int kg   = lane >> 5, m = lane & 31;

    // A fragment (one 32-x strip per wave) — layout verified R6
    union U { uint4 q; bf16x8 v; };
    U au;
    {
        int xi = b * NN + xb * XC + w * 32 + m;
        const float* xp = pred + (size_t)xi * 3;
        float x0 = xp[0], x1 = xp[1], x2 = xp[2];
        unsigned int h0 = f2bf(x0), h1 = f2bf(x1), h2 = f2bf(x2);
        unsigned int L0 = f2bf(x0 - bf2f(h0));
        unsigned int L1 = f2bf(x1 - bf2f(h1));
        unsigned int L2 = f2bf(x2 - bf2f(h2));
        float xsq = fmaf(x0, x0, fmaf(x1, x1, x2 * x2));
        unsigned int sh = f2bf(xsq);
        unsigned int sl = f2bf(xsq - bf2f(sh));
        au.q = make_uint4(kg ? (h2 | (sh << 16))    : (h0 | (h1 << 16)),
                          kg ? (sl | (ONEBF << 16)) : (h2 | (L0 << 16)),
                          kg ? ONEBF                : (L1 | (L2 << 16)),
                          kg ? 0u                   : (h0 | (h1 << 16)));
    }

    floatx16 acc, zacc;
#pragma unroll
    for (int r = 0; r < 16; ++r) { acc[r] = 3.402823466e38f; zacc[r] = 0.f; }

    // per-lane B base: record (b*NN + ys*YH + m) of this lane's kg array
    const uint4* bbase = (kg ? rec1 : rec0)
                       + (size_t)b * NN + (size_t)ys * YH + m;

#pragma unroll 4
    for (int t = 0; t < NTL; t += 2) {
        U bu0, bu1;
        bu0.q = bbase[(size_t)t * 32];          // global, L1/L2-served
        bu1.q = bbase[(size_t)(t + 1) * 32];
        floatx16 d0 = __builtin_amdgcn_mfma_f32_32x32x16_bf16(
            au.v, bu0.v, zacc, 0, 0, 0);
        floatx16 d1 = __builtin_amdgcn_mfma_f32_32x32x16_bf16(
            au.v, bu1.v, zacc, 0, 0, 0);
#pragma unroll
        for (int r = 0; r < 16; ++r)
            acc[r] = fminf(fminf(acc[r], d0[r]), d1[r]);   // v_min3
        float cp0 = tree16(d0);                 // col mins of each y-tile
        float cp1 = tree16(d1);
        cp0 = fminf(cp0, __shfl_xor(cp0, 32, 64));   // merge kg row-halves
        cp1 = fminf(cp1, __shfl_xor(cp1, 32, 64));
        if (kg == 0) {                          // each y-slot written once
            colp[w][t * 32 + m]       = cp0;
            colp[w][(t + 1) * 32 + m] = cp1;
        }
    }

    // rows: butterfly-min over 32 col-lanes, plain store
    float* rowbase = rowp + ((size_t)(b * YS + ys)) * NN + xb * XC;
#pragma unroll
    for (int r = 0; r < 16; ++r) {
        float v = acc[r];
        v = fminf(v, __shfl_xor(v, 1, 64));
        v = fminf(v, __shfl_xor(v, 2, 64));
        v = fminf(v, __shfl_xor(v, 4, 64));
        v = fminf(v, __shfl_xor(v, 8, 64));
        v = fminf(v, __shfl_xor(v, 16, 64));
        if (m == 0) {                           // lanes 0 and 32 both store
            int row = (r & 3) + 8 * (r >> 2) + 4 * kg;
            rowbase[w * 32 + row] = v;
        }
    }

    // cols: merge the 4 per-wave slices once, coalesced store
    __syncthreads();
    float* colbase = colf + (((size_t)(b * YS + ys)) * NXB + xb) * YH;
    for (int yl = tid; yl < YH; yl += T)
        colbase[yl] = fminf(fminf(colp[0][yl], colp[1][yl]),
                            fminf(colp[2][yl], colp[3][yl]));
}

// ---- final: rows 2-way, cols 32-way gather; clamp, sum, one atomic/block
__global__ __launch_bounds__(T) void chamfer_final(
    const float* __restrict__ rowp, const float* __restrict__ colf,
    float* __restrict__ out)
{
    int e = blockIdx.x * T + threadIdx.x;       // 0 .. 131071
    float v;
    if (e < NPTS) {                             // pred->target (rows)
        int b = e >> 12, x = e & (NN - 1);
        v = fminf(rowp[(size_t)(b * YS) * NN + x],
                  rowp[(size_t)(b * YS + 1) * NN + x]);
    } else {                                    // target->pred (cols)
        int f = e - NPTS;
        int b = f >> 12, y = f & (NN - 1);
        int ys = y >> 11, yl = y & (YH - 1);
        const float* p = colf + ((size_t)(b * YS + ys)) * NXB * YH + yl;
        v = 3.402823466e38f;
#pragma unroll
        for (int xb = 0; xb < NXB; ++xb) v = fminf(v, p[(size_t)xb * YH]);
    }
    float s = fmaxf(v, 0.f);
#pragma unroll
    for (int off = 32; off > 0; off >>= 1)
        s += __shfl_down(s, off, 64);
    __shared__ float wsum[4];
    if ((threadIdx.x & 63) == 0) wsum[threadIdx.x >> 6] = s;
    __syncthreads();
    if (threadIdx.x == 0) {
        float t = wsum[0] + wsum[1] + wsum[2] + wsum[3];
        atomicAdd(out, t * (1.0f / (BB * NN)));
    }
}

extern "C" void kernel_launch(void* const* d_in, const int* in_sizes, int n_in,
                              void* d_out, int out_size, void* d_ws, size_t ws_size,
                              hipStream_t stream) {
    const float* pred   = (const float*)d_in[0];
    const float* target = (const float*)d_in[1];
    // d_in[2] (batch, int64) ignored: sorted equal-size segments by construction.
    float* out  = (float*)d_out;
    uint4* rec0 = (uint4*)d_ws;                    // 1 MB
    uint4* rec1 = rec0 + NPTS;                     // 1 MB
    float* rowp = (float*)(rec1 + NPTS);           // 512 KB
    float* colf = rowp + (size_t)BB * YS * NN;     // 8 MB

    hipMemsetAsync(out, 0, sizeof(float), stream);
    chamfer_prep<<<NPTS / T, T, 0, stream>>>(target, rec0, rec1);
    dim3 grid(NXB, BB, YS);                        // 32 x 16 x 2 = 1024
    chamfer_main<<<grid, T, 0, stream>>>(pred, rec0, rec1, rowp, colf);
    chamfer_final<<<2 * NPTS / T, T, 0, stream>>>(rowp, colf, out);
}